// Round 2
// baseline (402.544 us; speedup 1.0000x reference)
//
#include <hip/hip_runtime.h>
#include <hip/hip_bf16.h>

typedef __bf16 bf16;
typedef __bf16 bf16x8 __attribute__((ext_vector_type(8)));
typedef __bf16 bf16x4 __attribute__((ext_vector_type(4)));
typedef float  f32x4  __attribute__((ext_vector_type(4)));

#define BM 128
#define BN 128
#define BK 32
#define LDK 40   // padded LDS row stride (bf16 elems): 80 B -> 16B-aligned rows, ~2-way banks

// C[M,N] = A[M,K] * B[N,K]^T  (both operands K-contiguous), split-bf16 (hi/lo) MFMA.
// Batched via blockIdx.z with element strides sAz/sBz/sCz.
__global__ __launch_bounds__(256) void gemm_bt_split(
    const float* __restrict__ A, const float* __restrict__ Bmat,
    float* __restrict__ C, int M, int N, int K,
    long sAz, long sBz, long sCz)
{
    __shared__ __align__(16) bf16 Ah[BM][LDK];
    __shared__ __align__(16) bf16 Al[BM][LDK];
    __shared__ __align__(16) bf16 Bh[BN][LDK];
    __shared__ __align__(16) bf16 Bl[BN][LDK];

    const int tid  = threadIdx.x;
    const int lane = tid & 63;
    const int wid  = tid >> 6;
    const int wm   = wid >> 1;          // 2x2 wave grid, each wave 64x64
    const int wn   = wid & 1;
    const int z    = blockIdx.z;
    const long aBase = (long)z * sAz;
    const long bBase = (long)z * sBz;
    const long cBase = (long)z * sCz;
    const int m0 = blockIdx.x * BM;
    const int n0 = blockIdx.y * BN;

    f32x4 acc[4][4];
#pragma unroll
    for (int i = 0; i < 4; ++i)
#pragma unroll
        for (int j = 0; j < 4; ++j) acc[i][j] = (f32x4)0.0f;

    const int lr = lane & 15;           // fragment row (A) / col (B)
    const int lk = (lane >> 4) * 8;     // fragment k-offset

    for (int kt = 0; kt < K; kt += BK) {
        __syncthreads();
        // ---- stage 128x32 f32 tiles of A and B, split into hi/lo bf16 ----
#pragma unroll
        for (int j = 0; j < 4; ++j) {
            const int idx = j * 256 + tid;     // quad index 0..1023
            const int r   = idx >> 3;          // 0..127
            const int c   = (idx & 7) * 4;     // 0,4,...,28
            const float4 va = *(const float4*)(A    + aBase + (long)(m0 + r) * K + kt + c);
            const float4 vb = *(const float4*)(Bmat + bBase + (long)(n0 + r) * K + kt + c);

            bf16x4 ah, al, bh, bl;
            ah.x = (bf16)va.x; al.x = (bf16)(va.x - (float)ah.x);
            ah.y = (bf16)va.y; al.y = (bf16)(va.y - (float)ah.y);
            ah.z = (bf16)va.z; al.z = (bf16)(va.z - (float)ah.z);
            ah.w = (bf16)va.w; al.w = (bf16)(va.w - (float)ah.w);
            bh.x = (bf16)vb.x; bl.x = (bf16)(vb.x - (float)bh.x);
            bh.y = (bf16)vb.y; bl.y = (bf16)(vb.y - (float)bh.y);
            bh.z = (bf16)vb.z; bl.z = (bf16)(vb.z - (float)bh.z);
            bh.w = (bf16)vb.w; bl.w = (bf16)(vb.w - (float)bh.w);

            *(bf16x4*)&Ah[r][c] = ah;
            *(bf16x4*)&Al[r][c] = al;
            *(bf16x4*)&Bh[r][c] = bh;
            *(bf16x4*)&Bl[r][c] = bl;
        }
        __syncthreads();

        // ---- fragments ----
        bf16x8 afh[4], afl[4], bfh[4], bfl[4];
#pragma unroll
        for (int i = 0; i < 4; ++i) {
            afh[i] = *(const bf16x8*)&Ah[wm * 64 + i * 16 + lr][lk];
            afl[i] = *(const bf16x8*)&Al[wm * 64 + i * 16 + lr][lk];
            bfh[i] = *(const bf16x8*)&Bh[wn * 64 + i * 16 + lr][lk];
            bfl[i] = *(const bf16x8*)&Bl[wn * 64 + i * 16 + lr][lk];
        }
        // ---- 3-product split MFMA: hi*hi + hi*lo + lo*hi ----
#pragma unroll
        for (int i = 0; i < 4; ++i)
#pragma unroll
            for (int j = 0; j < 4; ++j) {
                acc[i][j] = __builtin_amdgcn_mfma_f32_16x16x32_bf16(afh[i], bfh[j], acc[i][j], 0, 0, 0);
                acc[i][j] = __builtin_amdgcn_mfma_f32_16x16x32_bf16(afl[i], bfh[j], acc[i][j], 0, 0, 0);
                acc[i][j] = __builtin_amdgcn_mfma_f32_16x16x32_bf16(afh[i], bfl[j], acc[i][j], 0, 0, 0);
            }
    }

    // ---- epilogue: D lane mapping col = lane&15, row = (lane>>4)*4 + q ----
    const int rrow = (lane >> 4) * 4;
#pragma unroll
    for (int i = 0; i < 4; ++i)
#pragma unroll
        for (int j = 0; j < 4; ++j)
#pragma unroll
            for (int q = 0; q < 4; ++q) {
                C[cBase + (long)(m0 + wm * 64 + i * 16 + rrow + q) * N
                        + (n0 + wn * 64 + j * 16 + (lane & 15))] = acc[i][j][q];
            }
}

// In-place masked row softmax: data is [rows][SRCn] f32, row -> batch = row / TGTn.
__global__ __launch_bounds__(256) void softmax_mask_rows(
    float* __restrict__ data, const int* __restrict__ lens, int SRCn, int TGTn)
{
    const int row = blockIdx.x;
    const int b   = row / TGTn;
    const int len = lens[b];
    float* p = data + (long)row * SRCn;

    const int tid  = threadIdx.x;
    const int base = tid * 4;
    const int lane = tid & 63;
    const int wid  = tid >> 6;

    float4 v = *(const float4*)(p + base);
    float vals[4] = {v.x, v.y, v.z, v.w};

    float m = -INFINITY;
#pragma unroll
    for (int j = 0; j < 4; ++j)
        if (base + j < len) m = fmaxf(m, vals[j]);
#pragma unroll
    for (int off = 32; off >= 1; off >>= 1) m = fmaxf(m, __shfl_xor(m, off));

    __shared__ float redm[4];
    __shared__ float reds[4];
    if (lane == 0) redm[wid] = m;
    __syncthreads();
    m = fmaxf(fmaxf(redm[0], redm[1]), fmaxf(redm[2], redm[3]));

    float e[4];
    float s = 0.0f;
#pragma unroll
    for (int j = 0; j < 4; ++j) {
        e[j] = (base + j < len) ? __expf(vals[j] - m) : 0.0f;
        s += e[j];
    }
#pragma unroll
    for (int off = 32; off >= 1; off >>= 1) s += __shfl_xor(s, off);
    if (lane == 0) reds[wid] = s;
    __syncthreads();
    s = reds[0] + reds[1] + reds[2] + reds[3];

    const float inv = 1.0f / s;
    float4 o;
    o.x = e[0] * inv; o.y = e[1] * inv; o.z = e[2] * inv; o.w = e[3] * inv;
    *(float4*)(p + base) = o;
}

extern "C" void kernel_launch(void* const* d_in, const int* in_sizes, int n_in,
                              void* d_out, int out_size, void* d_ws, size_t ws_size,
                              hipStream_t stream)
{
    const float* source         = (const float*)d_in[0];  // [16,1024,1024]
    const float* memory_bank    = (const float*)d_in[1];  // [16,1024,1024]
    const int*   memory_lengths = (const int*)  d_in[2];  // [16]
    const float* W_in           = (const float*)d_in[3];  // [1024,1024]
    float* out = (float*)d_out;                           // [16,1024,1024]
    float* ht  = (float*)d_ws;                            // 16M f32 = 64 MB scratch

    const int Bb = 16, TGT = 1024, SRC = 1024, TD = 1024, SD = 1024;
    dim3 blk(256, 1, 1);

    // GEMM1: h_t[16384,1024] = source[16384,1024] @ W_in[1024,1024]^T
    gemm_bt_split<<<dim3((Bb * TGT) / BM, SD / BN, 1), blk, 0, stream>>>(
        source, W_in, ht, Bb * TGT, SD, TD, 0, 0, 0);

    // GEMM2 (batched): align[b][1024,1024] = h_t[b] @ memory_bank[b]^T -> raw scores into d_out
    gemm_bt_split<<<dim3(TGT / BM, SRC / BN, Bb), blk, 0, stream>>>(
        ht, memory_bank, out, TGT, SRC, SD,
        (long)TGT * SD, (long)SRC * SD, (long)TGT * SRC);

    // masked softmax over last dim, in place
    softmax_mask_rows<<<dim3(Bb * TGT, 1, 1), blk, 0, stream>>>(out, memory_lengths, SRC, TGT);
}